// Round 7
// baseline (170.420 us; speedup 1.0000x reference)
//
#include <hip/hip_runtime.h>

#define K      32
#define TPB    256
#define NB     1024                 // main blocks: 1024*256*8 = N
#define EPT    8                    // elements per thread (grid-stride)
#define NTOT   (32 * 64 * 1024)     // 2,097,152
#define STRIDE (TPB * NB)           // 262144

typedef float v2f __attribute__((ext_vector_type(2)));

__device__ __forceinline__ float wave_reduce_sum(float v) {
#pragma unroll
  for (int m = 1; m < 64; m <<= 1) v += __shfl_xor(v, m, 64);
  return v;
}

__device__ __forceinline__ float to_sgpr(float v) {
  return __int_as_float(__builtin_amdgcn_readfirstlane(__float_as_int(v)));
}

// Register control is STRUCTURAL (R0/R2: launch_bounds caps -> spill;
// R4: full e-unroll -> 256 VGPRs). R5 proved 'unroll 1' safe but it
// SERIALIZES the per-element dep chain (exp2->sq->sum->rcp->sAcc) and the
// kernel is latency-bound (VALUBusy ~33% at ~4 waves/SIMD). This round:
// 'unroll 2' = exactly two elements in flight (2x ILP, bounded live set),
// EPT=8 to amortize the block reduction, and single-kernel fusion via
// device-scope atomic counter (last block finalizes) to drop 2 dispatches.
__global__ __launch_bounds__(TPB)
void ssq_fused(const float* __restrict__ x, const float* __restrict__ bins,
               float* __restrict__ out, float* __restrict__ partials,
               unsigned int* __restrict__ counter) {
  const int tid  = threadIdx.x;
  const int base = blockIdx.x * TPB + tid;

  // wave-uniform -> SGPRs
  float binv[K];
#pragma unroll
  for (int k = 0; k < K; ++k) binv[k] = to_sgpr(bins[k]);
  float binsum = 0.f;
#pragma unroll
  for (int k = 0; k < K; ++k) binsum += binv[k];
  const float epsb = 1e-10f * binsum;    // eps * sum(bins) term of bit_code

  v2f binv2[K / 2];
#pragma unroll
  for (int i = 0; i < K / 2; ++i) binv2[i] = (v2f){binv[2 * i], binv[2 * i + 1]};

  float xs[EPT];
#pragma unroll
  for (int e = 0; e < EPT; ++e) xs[e] = x[base + e * STRIDE];

  v2f sAcc2[K / 2];
#pragma unroll
  for (int i = 0; i < K / 2; ++i) sAcc2[i] = (v2f){0.f, 0.f};
  float q = 0.f;

  const float Ch = -7.213475204444817f;   // 0.5 * ALPHA * log2(e)
  const v2f Ch2 = {Ch, Ch};

#pragma unroll 2
  for (int e = 0; e < EPT; ++e) {
    const float xv = xs[e];
    const v2f xv2 = {xv, xv};
    v2f t2[K / 2];                        // live only within this iteration
    v2f s2a = {0.f, 0.f}, s2b = {0.f, 0.f};
    v2f h2a = {0.f, 0.f}, h2b = {0.f, 0.f};
    v2f b2a = {0.f, 0.f}, b2b = {0.f, 0.f};
#pragma unroll
    for (int i = 0; i < K / 2; i += 2) {
      v2f d0 = xv2 - binv2[i];
      v2f d1 = xv2 - binv2[i + 1];
      v2f p0 = d0 * Ch2;
      v2f p1 = d1 * Ch2;
      v2f m0 = __builtin_elementwise_min(p0, -p0);   // = Ch*|d| (Ch<0)
      v2f m1 = __builtin_elementwise_min(p1, -p1);
      v2f h0 = {__builtin_amdgcn_exp2f(m0.x), __builtin_amdgcn_exp2f(m0.y)};
      v2f h1 = {__builtin_amdgcn_exp2f(m1.x), __builtin_amdgcn_exp2f(m1.y)};
      v2f t0 = h0 * h0;
      v2f t1 = h1 * h1;
      t2[i]     = t0;
      t2[i + 1] = t1;
      s2a += t0; s2b += t1;
      h2a += h0; h2b += h1;
      b2a += t0 * binv2[i];
      b2b += t1 * binv2[i + 1];
    }
    const v2f sv2 = (s2a + s2b);
    const v2f hv2 = (h2a + h2b);
    const v2f bv2 = (b2a + b2b);
    const float s    = sv2.x + sv2.y;
    const float hsum = hv2.x + hv2.y;
    const float bnum = bv2.x + bv2.y;
    const float inv  = __builtin_amdgcn_rcpf(s);
    q = fmaf(hsum, __builtin_amdgcn_rsqf(s), q);   // sum_k sqrt(a) = rsqrt(s)*sum h
    out[base + e * STRIDE] = fmaf(bnum, inv, epsb);
    const v2f inv2 = {inv, inv};
#pragma unroll
    for (int i = 0; i < K / 2; ++i) sAcc2[i] += t2[i] * inv2;
  }

  // block reduction: wave shuffle -> LDS -> one partial per counter per block
  __shared__ float red[4][K + 1];
  const int lane = tid & 63, wv = tid >> 6;
#pragma unroll
  for (int k = 0; k < K; ++k) {
    float v = wave_reduce_sum(sAcc2[k >> 1][k & 1]);
    if (lane == 0) red[wv][k] = v;
  }
  {
    float v = wave_reduce_sum(q);
    if (lane == 0) red[wv][K] = v;
  }
  __syncthreads();
  if (tid < K + 1) {
    float v = red[0][tid] + red[1][tid] + red[2][tid] + red[3][tid];
    partials[tid * NB + blockIdx.x] = v;   // written exactly once
  }

  // ---- last-block finalization (decoupled-lookback pattern) ----
  __shared__ unsigned int is_last;
  __threadfence();                          // release partials (device scope)
  if (tid == 0) is_last = (atomicAdd(counter, 1u) == NB - 1u);
  __syncthreads();
  if (!is_last) return;
  __threadfence();                          // acquire partials

  // 4 waves x 9 rows (wave w: rows 8w+r, last wave also row 32)
  __shared__ float sums[K + 1];
  const int nrows = (wv == 3) ? 9 : 8;
  for (int rr = 0; rr < nrows; ++rr) {
    const int c = (rr < 8) ? (wv * 8 + rr) : K;
    const float* p = partials + c * NB;
    float sl = 0.f;
#pragma unroll
    for (int j = 0; j < NB / 64; ++j) sl += p[lane + j * 64];
    sl = wave_reduce_sum(sl);
    if (lane == 0) sums[c] = sl;
  }
  __syncthreads();
  if (tid == 0) {
    const float invN = 1.0f / (float)NTOT;
    float ent = 0.f;
    for (int k = 0; k < K; ++k) {
      float pk = sums[k] * invN + 1e-10f;   // eps folded in analytically
      ent -= pk * __logf(pk);
    }
    out[NTOT + 0] = ent;                    // code entropy
    out[NTOT + 1] = 0.f;                    // TAU
    out[NTOT + 2] = sums[K] * invN;         // quant loss
    out[NTOT + 3] = 0.f;                    // TAU2
  }
}

extern "C" void kernel_launch(void* const* d_in, const int* in_sizes, int n_in,
                              void* d_out, int out_size, void* d_ws, size_t ws_size,
                              hipStream_t stream) {
  const float* x    = (const float*)d_in[0];
  const float* bins = (const float*)d_in[1];
  float* out        = (float*)d_out;
  float* partials   = (float*)d_ws;                       // (K+1)*NB floats
  unsigned int* ctr = (unsigned int*)(partials + (K + 1) * NB);

  hipMemsetAsync(ctr, 0, sizeof(unsigned int), stream);   // graph-capturable
  ssq_fused<<<NB, TPB, 0, stream>>>(x, bins, out, partials, ctr);
}

// Round 8
// 84.097 us; speedup vs baseline: 2.0265x; 2.0265x over previous
//
#include <hip/hip_runtime.h>

#define K      32
#define KH     16                   // bins per lane (K split across lane pairs)
#define TPB    256
#define NB     2048                 // blocks: 2048 * 128 pair-slots * 8 = N
#define EPT    8                    // elements per pair-slot
#define NTOT   (32 * 64 * 1024)     // 2,097,152
#define PSTRIDE (NB * (TPB / 2))    // 262144 pair-slots per sweep

__device__ __forceinline__ float wave_reduce_sum(float v) {
#pragma unroll
  for (int m = 1; m < 64; m <<= 1) v += __shfl_xor(v, m, 64);
  return v;
}

// reduce across lanes of the SAME parity (32 lanes): masks 2,4,8,16,32
__device__ __forceinline__ float pair_lane_reduce(float v) {
#pragma unroll
  for (int m = 2; m < 64; m <<= 1) v += __shfl_xor(v, m, 64);
  return v;
}

// Register-allocator failure modes catalogued: caps->spill (R0/R2),
// full e-unroll->256-reg balloon (R4), unroll2+arrays->scratch demotion
// (R7, VGPR=48, 119us). This round: HALVE the problem per lane instead.
// Lane pair (2j,2j+1) shares elements; each lane covers 16 bins. Chain/elem
// halves, arrays halve (t[16],sAcc[16],binv[16]), butterfly halves.
// e-loop stays 'unroll 1' (only proven-safe setting).
__global__ __launch_bounds__(TPB)
void ssq_main(const float* __restrict__ x, const float* __restrict__ bins,
              float* __restrict__ out, float* __restrict__ partials) {
  const int tid  = threadIdx.x;
  const int half = tid & 1;                       // which 16-bin half
  const int pslot = blockIdx.x * (TPB / 2) + (tid >> 1);

  // this lane's 16 bins (VGPRs -- parity-dependent, can't be SGPR)
  float binv[KH];
#pragma unroll
  for (int j = 0; j < KH; ++j) binv[j] = bins[KH * half + j];
  float bs_local = 0.f;
#pragma unroll
  for (int j = 0; j < KH; ++j) bs_local += binv[j];
  const float binsum = bs_local + __shfl_xor(bs_local, 1, 64);
  const float epsb = 1e-10f * binsum;             // eps * sum(bins) term

  float xs[EPT];
#pragma unroll
  for (int e = 0; e < EPT; ++e) xs[e] = x[pslot + e * PSTRIDE];

  float sAcc[KH];
#pragma unroll
  for (int j = 0; j < KH; ++j) sAcc[j] = 0.f;
  float q = 0.f;

  const float Ch = -7.213475204444817f;           // 0.5 * ALPHA * log2(e)

#pragma unroll 1
  for (int e = 0; e < EPT; ++e) {
    const float xv = xs[e];
    float t[KH];                                  // live only this iteration
    float s0 = 0.f, s1 = 0.f, h0 = 0.f, h1 = 0.f, b0 = 0.f, b1 = 0.f;
#pragma unroll
    for (int j = 0; j < KH; j += 2) {
      float ha = __builtin_amdgcn_exp2f(Ch * fabsf(xv - binv[j + 0]));
      float hb = __builtin_amdgcn_exp2f(Ch * fabsf(xv - binv[j + 1]));
      float ta = ha * ha, tb = hb * hb;
      t[j + 0] = ta; t[j + 1] = tb;
      s0 += ta; s1 += tb;
      h0 += ha; h1 += hb;
      b0 = fmaf(ta, binv[j + 0], b0);
      b1 = fmaf(tb, binv[j + 1], b1);
    }
    const float s_loc = s0 + s1;
    const float b_loc = b0 + b1;
    const float s_full = s_loc + __shfl_xor(s_loc, 1, 64);   // both halves
    const float b_full = b_loc + __shfl_xor(b_loc, 1, 64);
    const float inv = __builtin_amdgcn_rcpf(s_full);
    // local hsum * rsqrt(s): summing q over ALL lanes later gives sum_k sqrt(a_k)
    q = fmaf(h0 + h1, __builtin_amdgcn_rsqf(s_full), q);
    if (half == 0) out[pslot + e * PSTRIDE] = fmaf(b_full, inv, epsb);
#pragma unroll
    for (int j = 0; j < KH; ++j) sAcc[j] = fmaf(t[j], inv, sAcc[j]);
  }

  // block reduction. Same-parity butterfly: after it, lane0 holds bin j sum,
  // lane1 holds bin j+16 sum (for each of the 16 j's). q: full-wave reduce.
  __shared__ float red[4][K + 1];
  const int lane = tid & 63, wv = tid >> 6;
#pragma unroll
  for (int j = 0; j < KH; ++j) {
    float v = pair_lane_reduce(sAcc[j]);
    if (lane < 2) red[wv][KH * lane + j] = v;     // lane==half here
  }
  {
    float v = wave_reduce_sum(q);
    if (lane == 0) red[wv][K] = v;
  }
  __syncthreads();
  if (tid < K + 1) {
    float v = red[0][tid] + red[1][tid] + red[2][tid] + red[3][tid];
    partials[tid * NB + blockIdx.x] = v;          // written exactly once
  }
}

// 33 blocks: block c reduces partials[c*NB .. c*NB+NB) -> sums[c]
__global__ __launch_bounds__(TPB)
void ssq_reduce(const float* __restrict__ partials, float* __restrict__ sums) {
  const float* p = partials + blockIdx.x * NB;
  const int tid  = threadIdx.x;
  float s = 0.f;
#pragma unroll
  for (int j = 0; j < NB / TPB; ++j) s += p[tid + j * TPB];
  s = wave_reduce_sum(s);
  __shared__ float red[4];
  if ((tid & 63) == 0) red[tid >> 6] = s;
  __syncthreads();
  if (tid == 0) sums[blockIdx.x] = red[0] + red[1] + red[2] + red[3];
}

// one wave: entropy over 32 p_k + quant mean + tails
__global__ void ssq_final(const float* __restrict__ sums, float* __restrict__ out) {
  const int lane = threadIdx.x;
  float e = 0.f;
  if (lane < K) {
    float p = sums[lane] * (1.0f / (float)NTOT) + 1e-10f;  // eps folded in here
    e = -p * __logf(p);
  }
  e = wave_reduce_sum(e);
  if (lane == 0) {
    out[NTOT + 0] = e;                              // code entropy
    out[NTOT + 1] = 0.f;                            // TAU
    out[NTOT + 2] = sums[K] * (1.0f / (float)NTOT); // quant loss
    out[NTOT + 3] = 0.f;                            // TAU2
  }
}

extern "C" void kernel_launch(void* const* d_in, const int* in_sizes, int n_in,
                              void* d_out, int out_size, void* d_ws, size_t ws_size,
                              hipStream_t stream) {
  const float* x    = (const float*)d_in[0];
  const float* bins = (const float*)d_in[1];
  float* out        = (float*)d_out;
  float* partials   = (float*)d_ws;                 // (K+1)*NB floats = 264 KB
  float* sums       = partials + (K + 1) * NB;      // 33 floats

  ssq_main  <<<NB,    TPB, 0, stream>>>(x, bins, out, partials);
  ssq_reduce<<<K + 1, TPB, 0, stream>>>(partials, sums);
  ssq_final <<<1,     64,  0, stream>>>(sums, out);
}